// Round 5
// baseline (430.591 us; speedup 1.0000x reference)
//
#include <hip/hip_runtime.h>

// Problem constants (from setup_inputs): Npol=2, Nant=128, Nvis=8128, Nfreq=1024
constexpr int NANT  = 128;
constexpr int NVIS  = 8128;
constexpr int NFREQ = 1024;
constexpr int F2    = NFREQ / 2;      // one vec4 = 2 complex values along f
constexpr int VP    = NVIS * F2;      // V/out plane stride in vec4 units
constexpr int JP    = NANT * F2;      // jones plane stride in vec4 units

// Native clang vector type — required by __builtin_nontemporal_load/store
// (HIP_vector_type float4 is a class and is rejected by the builtin).
typedef float f4 __attribute__((ext_vector_type(4)));

__device__ __forceinline__ float2 lo2(f4 x) { return make_float2(x.x, x.y); }
__device__ __forceinline__ float2 hi2(f4 x) { return make_float2(x.z, x.w); }

// acc += x * y   (complex)
__device__ __forceinline__ float2 cfma(float2 x, float2 y, float2 acc) {
    acc.x = fmaf(x.x, y.x, fmaf(-x.y, y.y, acc.x));
    acc.y = fmaf(x.x, y.y, fmaf( x.y, y.x, acc.y));
    return acc;
}
// x * y  (complex)
__device__ __forceinline__ float2 cmul(float2 x, float2 y) {
    return make_float2(fmaf(x.x, y.x, -x.y * y.y),
                       fmaf(x.x, y.y,  x.y * y.x));
}
// acc += x * conj(y)
__device__ __forceinline__ float2 cfmac(float2 x, float2 y, float2 acc) {
    acc.x = fmaf(x.x, y.x, fmaf( x.y, y.y, acc.x));
    acc.y = fmaf(x.y, y.x, fmaf(-x.x, y.y, acc.y));
    return acc;
}
// x * conj(y)
__device__ __forceinline__ float2 cmulc(float2 x, float2 y) {
    return make_float2(fmaf(x.x, y.x,  x.y * y.y),
                       fmaf(x.y, y.x, -x.x * y.y));
}

__global__ __launch_bounds__(256) void jones_apply_kernel(
    const f4* __restrict__ Vm,    // [2][2][NVIS][F2] vec4
    const f4* __restrict__ J,     // [2][2][NANT][F2] vec4
    const int* __restrict__ ant1, // [NVIS]
    const int* __restrict__ ant2, // [NVIS]
    f4*       __restrict__ out)   // [2][2][NVIS][F2] vec4
{
    const int v  = blockIdx.y;                                // uniform per block
    const int f2 = blockIdx.x * blockDim.x + threadIdx.x;     // 0..F2-1

    const int a1 = ant1[v];   // block-uniform -> scalar load
    const int a2 = ant2[v];

    const int vbase  = v  * F2 + f2;
    const int j1base = a1 * F2 + f2;
    const int j2base = a2 * F2 + f2;

    // V planes: streamed once, bypass cache
    const f4 V00 = __builtin_nontemporal_load(&Vm[0 * VP + vbase]);
    const f4 V01 = __builtin_nontemporal_load(&Vm[1 * VP + vbase]);
    const f4 V10 = __builtin_nontemporal_load(&Vm[2 * VP + vbase]);
    const f4 V11 = __builtin_nontemporal_load(&Vm[3 * VP + vbase]);

    // Jones planes: heavily reused across visibilities -> normal (cached) loads
    const f4 J100 = J[0 * JP + j1base];
    const f4 J101 = J[1 * JP + j1base];
    const f4 J110 = J[2 * JP + j1base];
    const f4 J111 = J[3 * JP + j1base];

    const f4 J200 = J[0 * JP + j2base];
    const f4 J201 = J[1 * JP + j2base];
    const f4 J210 = J[2 * JP + j2base];
    const f4 J211 = J[3 * JP + j2base];

    float2 o[2][4];   // [freq slot][a*2+b]

    #pragma unroll
    for (int s = 0; s < 2; ++s) {
        const float2 v00 = s ? hi2(V00) : lo2(V00);
        const float2 v01 = s ? hi2(V01) : lo2(V01);
        const float2 v10 = s ? hi2(V10) : lo2(V10);
        const float2 v11 = s ? hi2(V11) : lo2(V11);

        const float2 j1_00 = s ? hi2(J100) : lo2(J100);
        const float2 j1_01 = s ? hi2(J101) : lo2(J101);
        const float2 j1_10 = s ? hi2(J110) : lo2(J110);
        const float2 j1_11 = s ? hi2(J111) : lo2(J111);

        const float2 j2_00 = s ? hi2(J200) : lo2(J200);
        const float2 j2_01 = s ? hi2(J201) : lo2(J201);
        const float2 j2_10 = s ? hi2(J210) : lo2(J210);
        const float2 j2_11 = s ? hi2(J211) : lo2(J211);

        // T[a][d] = sum_c J1[a][c] * V[c][d]
        const float2 t00 = cfma(j1_00, v00, cmul(j1_01, v10));
        const float2 t01 = cfma(j1_00, v01, cmul(j1_01, v11));
        const float2 t10 = cfma(j1_10, v00, cmul(j1_11, v10));
        const float2 t11 = cfma(j1_10, v01, cmul(j1_11, v11));

        // O[a][b] = sum_d T[a][d] * conj(J2[b][d])
        o[s][0] = cfmac(t00, j2_00, cmulc(t01, j2_01));   // a=0,b=0
        o[s][1] = cfmac(t00, j2_10, cmulc(t01, j2_11));   // a=0,b=1
        o[s][2] = cfmac(t10, j2_00, cmulc(t11, j2_01));   // a=1,b=0
        o[s][3] = cfmac(t10, j2_10, cmulc(t11, j2_11));   // a=1,b=1
    }

    #pragma unroll
    for (int p = 0; p < 4; ++p) {
        f4 r;
        r.x = o[0][p].x; r.y = o[0][p].y;
        r.z = o[1][p].x; r.w = o[1][p].y;
        __builtin_nontemporal_store(r, &out[p * VP + vbase]);
    }
}

extern "C" void kernel_launch(void* const* d_in, const int* in_sizes, int n_in,
                              void* d_out, int out_size, void* d_ws, size_t ws_size,
                              hipStream_t stream) {
    const f4*  Vm   = (const f4*)d_in[0];
    const f4*  J    = (const f4*)d_in[1];
    const int* ant1 = (const int*)d_in[2];
    const int* ant2 = (const int*)d_in[3];
    f4*        out  = (f4*)d_out;

    // grid: (F2/256, NVIS) -> f2 fully covered, v uniform per block
    dim3 grid(F2 / 256, NVIS);
    jones_apply_kernel<<<grid, dim3(256), 0, stream>>>(Vm, J, ant1, ant2, out);
}